// Round 14
// baseline (398.643 us; speedup 1.0000x reference)
//
#include <hip/hip_runtime.h>

// ---------------------------------------------------------------------------
// AugmentedMemoryScaledDotProductAttention on MI355X (gfx950)
// B=8 H=8 NQ=NK=1024 D_MODEL=1024 DK=DV=128 M=16  (NKM=1040, padded to 1088)
//
// R13: R12 (best, 392us) + (a) Q/K/V proj GEMMs merged with proj as the
// OUTER block index -- per-region mapping identical to standalone dispatch
// (no L2 interleave, unlike R10), only the dispatch-boundary tails overlap;
// (b) attn mask-word loads widened to uint2 (adjacent words, 8B-aligned).
// ---------------------------------------------------------------------------

typedef unsigned short u16;
typedef unsigned int   u32;
typedef _Float16 f16x8 __attribute__((ext_vector_type(8)));
typedef short    s16x8 __attribute__((ext_vector_type(8)));
typedef float    f32x4 __attribute__((ext_vector_type(4)));

#define MFMA_F16(a, b, c) __builtin_amdgcn_mfma_f32_16x16x32_f16((a), (b), (c), 0, 0, 0)

#define NQS    1024
#define NKM    1040      // NK + M
#define KSP    1088      // padded key stride (17 * 64)
#define MW     34        // mask words per row
#define SCALE_QK 0.088388347648318447f   // 1/sqrt(128)

__device__ __forceinline__ u16 f2h(float f) {
  _Float16 h = (_Float16)f;
  return __builtin_bit_cast(u16, h);
}
__device__ __forceinline__ f16x8 ld_h8(const u16* p) {
  s16x8 r = *(const s16x8*)p;
  return __builtin_bit_cast(f16x8, r);
}

// ---------------------------------------------------------------- elementwise
// merged f32->fp16 convert for q,k,v (outputs contiguous at ws+0)
__global__ void cvt16_all_kernel(const float* __restrict__ q,
                                 const float* __restrict__ k,
                                 const float* __restrict__ v,
                                 u16* __restrict__ out) {
  for (int i = blockIdx.x * blockDim.x + threadIdx.x; i < 6291456;
       i += gridDim.x * blockDim.x) {
    const int t = i >> 21, local = i & 2097151;
    const float* src = (t == 0) ? q : (t == 1) ? k : v;
    float4 x = ((const float4*)src)[local];
    ushort4 h;
    h.x = f2h(x.x); h.y = f2h(x.y); h.z = f2h(x.z); h.w = f2h(x.w);
    ((ushort4*)out)[i] = h;
  }
}

// merged LDS-tiled transpose for Wq/Wk/Wv/Wo: (in,out) rm -> (out,in) rm fp16
__global__ __launch_bounds__(256)
void wtrans16_all_kernel(const float* __restrict__ Wq, const float* __restrict__ Wk,
                         const float* __restrict__ Wv, const float* __restrict__ Wo,
                         u16* __restrict__ wq, u16* __restrict__ wk,
                         u16* __restrict__ wv, u16* __restrict__ wo) {
  __shared__ float t[64][65];
  const int wsel = blockIdx.x >> 8, bidx = blockIdx.x & 255;
  const float* w = (wsel == 0) ? Wq : (wsel == 1) ? Wk : (wsel == 2) ? Wv : Wo;
  u16* t16 = (wsel == 0) ? wq : (wsel == 1) ? wk : (wsel == 2) ? wv : wo;
  const int bx = bidx & 15;          // input-row (i) tile
  const int by = bidx >> 4;          // output-row (o) tile
  const int r = threadIdx.x >> 4, c4 = threadIdx.x & 15;
#pragma unroll
  for (int i = 0; i < 4; ++i) {
    const int row = bx * 64 + r + i * 16;
    float4 v = *(const float4*)&w[row * 1024 + by * 64 + c4 * 4];
    t[r + i * 16][c4 * 4 + 0] = v.x;
    t[r + i * 16][c4 * 4 + 1] = v.y;
    t[r + i * 16][c4 * 4 + 2] = v.z;
    t[r + i * 16][c4 * 4 + 3] = v.w;
  }
  __syncthreads();
  const int l = threadIdx.x & 63, og = threadIdx.x >> 6;
#pragma unroll
  for (int j = 0; j < 16; ++j) {
    const int o_local = og + j * 4;
    t16[(by * 64 + o_local) * 1024 + bx * 64 + l] = f2h(t[l][o_local]);
  }
}

// merged memory-slot fills + mask tail words.
__global__ void fill_all_kernel(const float* __restrict__ m_k,
                                const float* __restrict__ m_v,
                                u16* __restrict__ kh, u16* __restrict__ vt,
                                u32* __restrict__ mbits) {
  const int bi = blockIdx.x;
  if (bi < 2048) {
    int idx = bi * 256 + threadIdx.x;           // 64*64*128 = 524288
    int bh = idx >> 13, ko = (idx >> 7) & 63, dk = idx & 127;
    int h = bh & 7;
    float v = 0.f;
    if (ko < 16) v = 11.313708498984760f * m_k[ko * 1024 + h * 128 + dk];
    kh[((size_t)bh * KSP + 1024 + ko) * 128 + dk] = f2h(v);
  } else if (bi < 4096) {
    int idx = (bi - 2048) * 256 + threadIdx.x;  // 64*128*64 = 524288
    int bh = idx >> 13, dv = (idx >> 6) & 127, ko = idx & 63;
    int h = bh & 7;
    float v = (ko < 16) ? 4.0f * m_v[ko * 1024 + h * 128 + dv] : 0.f;
    vt[((size_t)bh * 128 + dv) * KSP + 1024 + ko] = f2h(v);
  } else {
    int idx = (bi - 4096) * 256 + threadIdx.x;  // 65536
    mbits[idx * MW + 32] = 0xFFFF0000u;
    mbits[idx * MW + 33] = 0xFFFFFFFFu;
  }
}

// mask (int32, !=0 dead) -> bit words. mbits[(bh*1024+q)*34 + w].
__global__ void maskbits_kernel(const int* __restrict__ mask, u32* __restrict__ mbits) {
  const int lane = threadIdx.x & 63;
  const int nwave = (gridDim.x * blockDim.x) >> 6;
  int wid = (blockIdx.x * blockDim.x + threadIdx.x) >> 6;
  for (int g = wid; g < 262144; g += nwave) {       // 256-key groups
    const int4 m = *(const int4*)&mask[(size_t)g * 256 + lane * 4];
    u32 nib = (m.x ? 1u : 0u) | (m.y ? 2u : 0u) | (m.z ? 4u : 0u) | (m.w ? 8u : 0u);
    u32 v = nib << ((lane & 7) * 4);
    v |= __shfl_xor(v, 1);
    v |= __shfl_xor(v, 2);
    v |= __shfl_xor(v, 4);
    if ((lane & 7) == 0) {
      const int row = g >> 2;                        // (bh*1024+q)
      const int word = ((g & 3) << 3) + (lane >> 3); // 0..31
      mbits[row * MW + word] = v;
    }
  }
}

// ---------------------------------------------------------------------- GEMM
// C(8192x1024) = A(8192x1024) @ B^T, B given as (1024 n-rows x 1024 k) rm.
// 128x128 tile, BK=64, 4 waves (2x2), 4x4 16x16x32 fp16 fragments per wave.
// R7 mapping: bm inner, bn outer (within each proj region).
__device__ __forceinline__ void stage_tile(const u16* __restrict__ gbase,
                                           u16* sbase, int w, int lane) {
#pragma unroll
  for (int i = 0; i < 4; ++i) {
    const u16* src = gbase + (w * 32 + i * 8 + (lane >> 3)) * 1024 + (lane & 7) * 8;
    u16* dst = sbase + (w * 32 + i * 8) * 64;
    __builtin_amdgcn_global_load_lds(
        (const __attribute__((address_space(1))) void*)src,
        (__attribute__((address_space(3))) void*)dst, 16, 0, 0);
  }
}

// merged Q/K/V projection GEMM, proj OUTER: blocks [0,512)=Q, [512,1024)=K,
// [1024,1536)=V. Within a region: bm = idx & 63 (inner), bn = idx >> 6.
__global__ __launch_bounds__(256)
void gemm_proj_kernel(const u16* __restrict__ xq, const u16* __restrict__ xk,
                      const u16* __restrict__ xv,
                      const u16* __restrict__ wq, const u16* __restrict__ wk,
                      const u16* __restrict__ wv,
                      const float* __restrict__ bq, const float* __restrict__ bk,
                      const float* __restrict__ bv,
                      u16* __restrict__ q16, u16* __restrict__ k16,
                      u16* __restrict__ vt) {
  __shared__ u16 sA[128 * 64];
  __shared__ u16 sB[128 * 64];
  const int lane = threadIdx.x & 63, w = threadIdx.x >> 6;
  const int proj = blockIdx.x >> 9;          // 0,1,2
  const int idx = blockIdx.x & 511;
  const int bm = idx & 63, bn = idx >> 6;
  const u16* A = (proj == 0) ? xq : (proj == 1) ? xk : xv;
  const u16* B = (proj == 0) ? wq : (proj == 1) ? wk : wv;
  const float* bias = (proj == 0) ? bq : (proj == 1) ? bk : bv;
  const int wr = w >> 1, wc = w & 1;

  f32x4 acc[4][4];
  const f32x4 fz = {0.f, 0.f, 0.f, 0.f};
#pragma unroll
  for (int m = 0; m < 4; ++m)
#pragma unroll
    for (int n = 0; n < 4; ++n) acc[m][n] = fz;

  for (int kt = 0; kt < 16; ++kt) {
    const int kb = kt * 64;
    stage_tile(A + bm * 128 * 1024 + kb, sA, w, lane);
    stage_tile(B + bn * 128 * 1024 + kb, sB, w, lane);
    __syncthreads();
    const int ro = lane & 15;
#pragma unroll
    for (int kk = 0; kk < 2; ++kk) {
      const int co = kk * 32 + (lane >> 4) * 8;
      f16x8 a[4], b[4];
#pragma unroll
      for (int m = 0; m < 4; ++m) a[m] = ld_h8(&sA[(wr * 64 + m * 16 + ro) * 64 + co]);
#pragma unroll
      for (int n = 0; n < 4; ++n) b[n] = ld_h8(&sB[(wc * 64 + n * 16 + ro) * 64 + co]);
#pragma unroll
      for (int m = 0; m < 4; ++m)
#pragma unroll
        for (int n = 0; n < 4; ++n)
          acc[m][n] = MFMA_F16(a[m], b[n], acc[m][n]);
    }
    __syncthreads();
  }

#pragma unroll
  for (int m = 0; m < 4; ++m)
#pragma unroll
    for (int n = 0; n < 4; ++n) {
      const int row0 = bm * 128 + wr * 64 + m * 16 + ((lane >> 4) << 2);
      const int col = bn * 128 + wc * 64 + n * 16 + (lane & 15);
      const float bv_ = bias[col];
#pragma unroll
      for (int r = 0; r < 4; ++r) {
        const float y = acc[m][n][r] + bv_;
        const int row = row0 + r;
        if (proj == 0) {
          q16[row * 1024 + col] = f2h(y * SCALE_QK);   // scale folded into Q
        } else if (proj == 1) {
          const int b = row >> 10, key = row & 1023;
          k16[((size_t)(b * 8 + (col >> 7)) * KSP + key) * 128 + (col & 127)] = f2h(y);
        } else {
          const int b = row >> 10, key = row & 1023;
          vt[((size_t)(b * 8 + (col >> 7)) * 128 + (col & 127)) * KSP + key] = f2h(y);
        }
      }
    }
}

// output projection GEMM (f32 out), R7 mapping
__global__ __launch_bounds__(256)
void gemm_out_kernel(const u16* __restrict__ A, const u16* __restrict__ B,
                     const float* __restrict__ bias, float* __restrict__ oF) {
  __shared__ u16 sA[128 * 64];
  __shared__ u16 sB[128 * 64];
  const int lane = threadIdx.x & 63, w = threadIdx.x >> 6;
  const int bm = blockIdx.x & 63, bn = blockIdx.x >> 6;
  const int wr = w >> 1, wc = w & 1;

  f32x4 acc[4][4];
  const f32x4 fz = {0.f, 0.f, 0.f, 0.f};
#pragma unroll
  for (int m = 0; m < 4; ++m)
#pragma unroll
    for (int n = 0; n < 4; ++n) acc[m][n] = fz;

  for (int kt = 0; kt < 16; ++kt) {
    const int kb = kt * 64;
    stage_tile(A + bm * 128 * 1024 + kb, sA, w, lane);
    stage_tile(B + bn * 128 * 1024 + kb, sB, w, lane);
    __syncthreads();
    const int ro = lane & 15;
#pragma unroll
    for (int kk = 0; kk < 2; ++kk) {
      const int co = kk * 32 + (lane >> 4) * 8;
      f16x8 a[4], b[4];
#pragma unroll
      for (int m = 0; m < 4; ++m) a[m] = ld_h8(&sA[(wr * 64 + m * 16 + ro) * 64 + co]);
#pragma unroll
      for (int n = 0; n < 4; ++n) b[n] = ld_h8(&sB[(wc * 64 + n * 16 + ro) * 64 + co]);
#pragma unroll
      for (int m = 0; m < 4; ++m)
#pragma unroll
        for (int n = 0; n < 4; ++n)
          acc[m][n] = MFMA_F16(a[m], b[n], acc[m][n]);
    }
    __syncthreads();
  }

#pragma unroll
  for (int m = 0; m < 4; ++m)
#pragma unroll
    for (int n = 0; n < 4; ++n) {
      const int row0 = bm * 128 + wr * 64 + m * 16 + ((lane >> 4) << 2);
      const int col = bn * 128 + wc * 64 + n * 16 + (lane & 15);
      const float bv_ = bias[col];
#pragma unroll
      for (int r = 0; r < 4; ++r)
        oF[(row0 + r) * 1024 + col] = acc[m][n][r] + bv_;
    }
}

// ----------------------------------------------------------------- attention
// R7-verified structure. 4 waves/block, 16 q-rows/wave, 1024 blocks (64 bh x
// 16 qblk, bh-per-XCD). Phase 1: 17 x 64-key chunks, QK^T+exp -> lsum only.
// Shuffle-reduce -> inv[4] in regs. Phase 2: 17 x 64-key chunks, QK^T
// recomputed (K L2-hot), e*inv -> normalized att + PV. T14 reg-staging,
// XOR-swizzled K LDS. Mask words loaded as uint2 (adjacent, 8B-aligned).
__global__ __launch_bounds__(256, 3)
void attn_kernel(const u16* __restrict__ qh, const u16* __restrict__ kh,
                 const u16* __restrict__ vt, const u32* __restrict__ mbits,
                 float* __restrict__ att, u16* __restrict__ obuf) {
  __shared__ __align__(16) u16 sK[64 * 128];        // 16 KB
  __shared__ __align__(16) u16 sV[128 * 72];        // 18 KB (144B rows)
  __shared__ __align__(16) float sAtt[4][16][36];   // 9 KB
  const int tid = threadIdx.x;
  const int lane = tid & 63, w = tid >> 6;

  // XCD swizzle: XCD x owns bh in [x*8, x*8+8), 16 qblks each.
  const int d = blockIdx.x;                  // 1024 blocks
  const int j = d >> 3;
  const int bh = (d & 7) * 8 + (j >> 4);
  const int qblk = j & 15;
  const int h = bh & 7;
  const int b = bh >> 3;
  const int qrow0 = qblk * 64 + w * 16;       // within NQ
  const int grow0 = b * NQS + qrow0;          // row in (8192 x 1024) Q/O buffers
  const int ro = lane & 15, go = lane >> 4;

  // Q fragments (held for whole kernel)
  f16x8 qf[4];
#pragma unroll
  for (int kk = 0; kk < 4; ++kk)
    qf[kk] = ld_h8(&qh[(grow0 + ro) * 1024 + h * 128 + kk * 32 + go * 8]);

  const u16* khb = kh + (size_t)bh * KSP * 128;
  const u16* vtb = vt + (size_t)bh * 128 * KSP;
  const u32* mbb = mbits + (size_t)bh * NQS * MW;
  float* attb = att + (size_t)(bh * NQS + qrow0) * NKM;

  // K staging geometry: 4 x 16B per thread (rows r_k, +16, +32, +48)
  const int r_k  = tid >> 4;               // 0..15
  const int cb_k = (tid & 15) * 16;        // byte col in 256B row
  const u16* kp0 = khb + r_k * 128 + (cb_k >> 1);
  const int dk0 = r_k * 256 + (cb_k ^ ((r_k & 7) << 4));   // xor invariant to +16 rows
  // V staging geometry: 4 x 16B per thread; t = p*256+tid: row t>>3, chunk t&7
  const int vrow[4] = {(0 * 256 + tid) >> 3, (1 * 256 + tid) >> 3,
                       (2 * 256 + tid) >> 3, (3 * 256 + tid) >> 3};
  const int vc8[4]  = {(0 * 256 + tid) & 7, (1 * 256 + tid) & 7,
                       (2 * 256 + tid) & 7, (3 * 256 + tid) & 7};

  const f32x4 fz = {0.f, 0.f, 0.f, 0.f};
  float lsum[4] = {0.f, 0.f, 0.f, 0.f};

  // ================= phase 1: row sums (17 x 64-key chunks) ===============
  {
    s16x8 rk0 = *(const s16x8*)(kp0);
    s16x8 rk1 = *(const s16x8*)(kp0 + 16 * 128);
    s16x8 rk2 = *(const s16x8*)(kp0 + 32 * 128);
    s16x8 rk3 = *(const s16x8*)(kp0 + 48 * 128);
    for (int c = 0; c < 17; ++c) {
      __syncthreads();
      *(s16x8*)((char*)sK + dk0)         = rk0;
      *(s16x8*)((char*)sK + dk0 + 4096)  = rk1;
      *(s16x8*)((char*)sK + dk0 + 8192)  = rk2;
      *(s16x8*)((char*)sK + dk0 + 12288) = rk3;
      if (c < 16) {
        const u16* p = kp0 + (c + 1) * 64 * 128;
        rk0 = *(const s16x8*)(p);
        rk1 = *(const s16x8*)(p + 16 * 128);
        rk2 = *(const s16x8*)(p + 32 * 128);
        rk3 = *(const s16x8*)(p + 48 * 128);
      }
      __syncthreads();
      u32 mw0[4], mw1[4];
#pragma unroll
      for (int r = 0; r < 4; ++r) {
        const int row = qrow0 + (go << 2) + r;
        uint2 mm = *(const uint2*)&mbb[row * MW + 2 * c];
        mw0[r] = mm.x;
        mw1[r] = mm.y;
      }
#pragma unroll
      for (int t = 0; t < 4; ++t) {
        f32x4 s = fz;
        const int rr = t * 16 + ro;
        const int sw = (rr & 7) << 4;
        __builtin_amdgcn_s_setprio(1);
#pragma unroll
        for (int kk = 0; kk < 4; ++kk) {
          const int off = rr * 256 + ((kk * 64 + go * 16) ^ sw);
          s = MFMA_F16(qf[kk], ld_h8((const u16*)((const char*)sK + off)), s);
        }
        __builtin_amdgcn_s_setprio(0);
        const int bit = (t & 1) * 16 + ro;
#pragma unroll
        for (int r = 0; r < 4; ++r) {
          const u32 mw = (t < 2) ? mw0[r] : mw1[r];
          const bool dead = (mw >> bit) & 1;
          lsum[r] += dead ? 0.f : __expf(s[r]);
        }
      }
    }
  }

  // reduce across the 16 ro-lanes of each go-group -> every lane holds inv[]
  float inv[4];
#pragma unroll
  for (int r = 0; r < 4; ++r) {
    lsum[r] += __shfl_xor(lsum[r], 1);
    lsum[r] += __shfl_xor(lsum[r], 2);
    lsum[r] += __shfl_xor(lsum[r], 4);
    lsum[r] += __shfl_xor(lsum[r], 8);
    inv[r] = 1.0f / lsum[r];
  }

  // ================= phase 2: normalized att + PV =========================
  f32x4 oacc[8];
#pragma unroll
  for (int n = 0; n < 8; ++n) oacc[n] = fz;

  s16x8 rk0 = *(const s16x8*)(kp0);
  s16x8 rk1 = *(const s16x8*)(kp0 + 16 * 128);
  s16x8 rk2 = *(const s16x8*)(kp0 + 32 * 128);
  s16x8 rk3 = *(const s16x8*)(kp0 + 48 * 128);
  s16x8 rv0 = *(const s16x8*)(vtb + (size_t)vrow[0] * KSP + vc8[0] * 8);
  s16x8 rv1 = *(const s16x8*)(vtb + (size_t)vrow[1] * KSP + vc8[1] * 8);
  s16x8 rv2 = *(const s16x8*)(vtb + (size_t)vrow[2] * KSP + vc8[2] * 8);
  s16x8 rv3 = *(const s16x8*)(vtb + (size_t)vrow[3] * KSP + vc8[3] * 8);

  for (int c = 0; c < 17; ++c) {
    __syncthreads();                       // previous chunk fully consumed
    *(s16x8*)((char*)sK + dk0)         = rk0;
    *(s16x8*)((char*)sK + dk0 + 4096)  = rk1;
    *(s16x8*)((char*)sK + dk0 + 8192)  = rk2;
    *(s16x8*)((char*)sK + dk0 + 12288) = rk3;
    *(s16x8*)((char*)sV + vrow[0] * 144 + vc8[0] * 16) = rv0;
    *(s16x8*)((char*)sV + vrow[1] * 144 + vc8[1] * 16) = rv1;
    *(s16x8*)((char*)sV + vrow[2] * 144 + vc8[2] * 16) = rv2;
    *(s16x8*)((char*)sV + vrow[3] * 144 + vc8[3] * 16) = rv3;
    if (c < 16) {                          // issue next chunk's loads
      const int nkb = (c + 1) * 64;
      const u16* p = kp0 + nkb * 128;
      rk0 = *(const s16x8*)(p);
      rk1 = *(const s16x8*)(p + 16 * 128);
      rk2 = *(const s16x8*)(p + 32 * 128);
      rk3 = *(const s16x8*)(p + 48 * 128);
      rv0 = *(const s16x8*)(vtb + (size_t)vrow[0] * KSP + nkb + vc8[0] * 8);
      rv1 = *(const s16x8*)(vtb + (size_t)vrow[1] * KSP + nkb + vc8[1] * 8);
      rv2 = *(const s16x8*)(vtb + (size_t)vrow[2] * KSP + nkb + vc8[2] * 8);
      rv3 = *(const s16x8*)(vtb + (size_t)vrow[3] * KSP + nkb + vc8[3] * 8);
    }
    __syncthreads();                       // chunk c ready

    u32 mwc[2][4];
#pragma unroll
    for (int r = 0; r < 4; ++r) {
      const int row = qrow0 + (go << 2) + r;
      uint2 mm = *(const uint2*)&mbb[row * MW + 2 * c];
      mwc[0][r] = mm.x;
      mwc[1][r] = mm.y;
    }

#pragma unroll
    for (int t2 = 0; t2 < 2; ++t2) {
#pragma unroll
      for (int t = 0; t < 2; ++t) {
        f32x4 s = fz;
        const int rr = t2 * 32 + t * 16 + ro;        // key row in 64-chunk
        const int sw = (rr & 7) << 4;
        __builtin_amdgcn_s_setprio(1);
#pragma unroll
        for (int kk = 0; kk < 4; ++kk) {
          const int off = rr * 256 + ((kk * 64 + go * 16) ^ sw);
          s = MFMA_F16(qf[kk], ld_h8((const u16*)((const char*)sK + off)), s);
        }
        __builtin_amdgcn_s_setprio(0);
        const int bit = t * 16 + ro;
#pragma unroll
        for (int r = 0; r < 4; ++r) {
          const int lrow = (go << 2) + r;
          const bool dead = (mwc[t2][r] >> bit) & 1;
          const float e = dead ? 0.f : __expf(s[r]);
          sAtt[w][lrow][t * 16 + ro] = e * inv[r];   // normalized
        }
      }

      // att writeout (normalized): 4 lanes cover one row's 32 f32 (128B)
      {
        const int kbh = c * 64 + t2 * 32;
        const int arow = lane >> 2, cg = lane & 3;
        if (kbh + cg * 8 < NKM) {
          f32x4 v0 = *(const f32x4*)&sAtt[w][arow][cg * 8];
          f32x4 v1 = *(const f32x4*)&sAtt[w][arow][cg * 8 + 4];
          float* dst = attb + (size_t)arow * NKM + kbh + cg * 8;
          *(f32x4*)dst = v0;
          *(f32x4*)(dst + 4) = v1;
        }
      }

      // PV with normalized p (A rows=q, cols=key), B rows=dv from sV
      {
        f32x4 p0 = *(const f32x4*)&sAtt[w][ro][go * 8];
        f32x4 p1 = *(const f32x4*)&sAtt[w][ro][go * 8 + 4];
        f16x8 pa;
        pa[0] = (_Float16)p0[0]; pa[1] = (_Float16)p0[1];
        pa[2] = (_Float16)p0[2]; pa[3] = (_Float16)p0[3];
        pa[4] = (_Float16)p1[0]; pa[5] = (_Float16)p1[1];
        pa[6] = (_Float16)p1[2]; pa[7] = (_Float16)p1[3];
        __builtin_amdgcn_s_setprio(1);
#pragma unroll
        for (int n = 0; n < 8; ++n) {
          f16x8 vb = ld_h8((const u16*)((const char*)sV + (n * 16 + ro) * 144 + t2 * 64 + go * 16));
          oacc[n] = MFMA_F16(pa, vb, oacc[n]);
        }
        __builtin_amdgcn_s_setprio(0);
      }
    }
  }

  // O writeout via LDS re-tile: wave w stages 16 rows x 128 cols fp16 at
  // sK + w*4096, then 16B coalesced stores (16 lanes cover one 256B row).
  __syncthreads();
  {
    u16* os = (u16*)((char*)sK + w * 4096);
#pragma unroll
    for (int n = 0; n < 8; ++n)
#pragma unroll
      for (int r = 0; r < 4; ++r)
        os[((go << 2) + r) * 128 + n * 16 + ro] = f2h(oacc[n][r]);
#pragma unroll
    for (int i = 0; i < 4; ++i) {
      const int idx = i * 64 + lane;            // 0..255
      const int row = idx >> 4, c16 = idx & 15; // 16 rows x 16 chunks
      s16x8 v = *(const s16x8*)(os + row * 128 + c16 * 8);
      *(s16x8*)&obuf[(size_t)(grow0 + row) * 1024 + h * 128 + c16 * 8] = v;
    }
  }
}

// --------------------------------------------------------------------- launch
extern "C" void kernel_launch(void* const* d_in, const int* in_sizes, int n_in,
                              void* d_out, int out_size, void* d_ws, size_t ws_size,
                              hipStream_t stream) {
  const float* queries = (const float*)d_in[0];
  const float* keys    = (const float*)d_in[1];
  const float* values  = (const float*)d_in[2];
  const int*   mask    = (const int*)d_in[3];
  const float* Wq = (const float*)d_in[4];
  const float* bq = (const float*)d_in[5];
  const float* Wk = (const float*)d_in[6];
  const float* bk = (const float*)d_in[7];
  const float* Wv = (const float*)d_in[8];
  const float* bv = (const float*)d_in[9];
  const float* Wo = (const float*)d_in[10];
  const float* bo = (const float*)d_in[11];
  const float* m_k = (const float*)d_in[12];
  const float* m_v = (const float*)d_in[13];

  if (ws_size < 136839168) return;   // layout below needs ~130.5 MiB

  char* ws = (char*)d_ws;
  u16* xq  = (u16*)(ws + 0);           // 16 MiB (xq/xk/xv contiguous)
  u16* xk  = (u16*)(ws + 16777216);    // 16 MiB
  u16* xv  = (u16*)(ws + 33554432);    // 16 MiB
  u16* wq  = (u16*)(ws + 50331648);    // 2 MiB
  u16* wk  = (u16*)(ws + 52428800);
  u16* wv  = (u16*)(ws + 54525952);
  u16* wo  = (u16*)(ws + 56623104);
  u16* q16 = (u16*)(ws + 58720256);    // 16 MiB
  u16* k16 = (u16*)(ws + 75497472);    // 64*1088*128*2 = 17 MiB
  u16* vt  = (u16*)(ws + 93323264);    // 17 MiB
  u16* obuf= (u16*)(ws + 111149056);   // 16 MiB
  u32* mbits=(u32*)(ws + 127926272);   // 8.9 MiB

  float* out = (float*)d_out;
  float* att = out + 8388608;

  // 1. input converts (f32 -> fp16), one dispatch
  cvt16_all_kernel<<<6144, 256, 0, stream>>>(queries, keys, values, xq);
  // 2. weight transposes (LDS-tiled, fp16), one dispatch
  wtrans16_all_kernel<<<1024, 256, 0, stream>>>(Wq, Wk, Wv, Wo, wq, wk, wv, wo);
  // 3. merged Q/K/V projections, proj-outer (per-region mapping == R12)
  gemm_proj_kernel<<<1536, 256, 0, stream>>>(xq, xk, xv, wq, wk, wv,
                                             bq, bk, bv, q16, k16, vt);
  // 4. mask bit-pack
  maskbits_kernel<<<2048, 256, 0, stream>>>(mask, mbits);
  // 5. memory-slot fills + mask tail words, one dispatch
  fill_all_kernel<<<4352, 256, 0, stream>>>(m_k, m_v, k16, vt, mbits);
  // 6. attention (normalized att + O in one kernel, two-pass over K)
  attn_kernel<<<1024, 256, 0, stream>>>(q16, k16, vt, mbits, att, obuf);
  // 7. output projection
  gemm_out_kernel<<<512, 256, 0, stream>>>(obuf, wo, bo, out);
}

// Round 15
// 391.900 us; speedup vs baseline: 1.0172x; 1.0172x over previous
//
#include <hip/hip_runtime.h>

// ---------------------------------------------------------------------------
// AugmentedMemoryScaledDotProductAttention on MI355X (gfx950)
// B=8 H=8 NQ=NK=1024 D_MODEL=1024 DK=DV=128 M=16  (NKM=1040, padded to 1088)
//
// R14 (final): R12's verified-best configuration (391.9 us) -- separate
// 128x128 proj GEMMs (R7 mapping), R7 two-pass attn (f32 sAtt, 17x64
// chunks, XOR-swizzled K, T14 reg-staging), merged cvt/wtrans/fill
// dispatches. Only delta vs R12: uint2 mask-word loads (codegen-neutral).
// R13's proj merge reverted (regressed twice: R10 interleaved, R13 outer).
// ---------------------------------------------------------------------------

typedef unsigned short u16;
typedef unsigned int   u32;
typedef _Float16 f16x8 __attribute__((ext_vector_type(8)));
typedef short    s16x8 __attribute__((ext_vector_type(8)));
typedef float    f32x4 __attribute__((ext_vector_type(4)));

#define MFMA_F16(a, b, c) __builtin_amdgcn_mfma_f32_16x16x32_f16((a), (b), (c), 0, 0, 0)

#define NQS    1024
#define NKM    1040      // NK + M
#define KSP    1088      // padded key stride (17 * 64)
#define MW     34        // mask words per row
#define SCALE_QK 0.088388347648318447f   // 1/sqrt(128)

__device__ __forceinline__ u16 f2h(float f) {
  _Float16 h = (_Float16)f;
  return __builtin_bit_cast(u16, h);
}
__device__ __forceinline__ f16x8 ld_h8(const u16* p) {
  s16x8 r = *(const s16x8*)p;
  return __builtin_bit_cast(f16x8, r);
}

// ---------------------------------------------------------------- elementwise
// merged f32->fp16 convert for q,k,v (outputs contiguous at ws+0)
__global__ void cvt16_all_kernel(const float* __restrict__ q,
                                 const float* __restrict__ k,
                                 const float* __restrict__ v,
                                 u16* __restrict__ out) {
  for (int i = blockIdx.x * blockDim.x + threadIdx.x; i < 6291456;
       i += gridDim.x * blockDim.x) {
    const int t = i >> 21, local = i & 2097151;
    const float* src = (t == 0) ? q : (t == 1) ? k : v;
    float4 x = ((const float4*)src)[local];
    ushort4 h;
    h.x = f2h(x.x); h.y = f2h(x.y); h.z = f2h(x.z); h.w = f2h(x.w);
    ((ushort4*)out)[i] = h;
  }
}

// merged LDS-tiled transpose for Wq/Wk/Wv/Wo: (in,out) rm -> (out,in) rm fp16
__global__ __launch_bounds__(256)
void wtrans16_all_kernel(const float* __restrict__ Wq, const float* __restrict__ Wk,
                         const float* __restrict__ Wv, const float* __restrict__ Wo,
                         u16* __restrict__ wq, u16* __restrict__ wk,
                         u16* __restrict__ wv, u16* __restrict__ wo) {
  __shared__ float t[64][65];
  const int wsel = blockIdx.x >> 8, bidx = blockIdx.x & 255;
  const float* w = (wsel == 0) ? Wq : (wsel == 1) ? Wk : (wsel == 2) ? Wv : Wo;
  u16* t16 = (wsel == 0) ? wq : (wsel == 1) ? wk : (wsel == 2) ? wv : wo;
  const int bx = bidx & 15;          // input-row (i) tile
  const int by = bidx >> 4;          // output-row (o) tile
  const int r = threadIdx.x >> 4, c4 = threadIdx.x & 15;
#pragma unroll
  for (int i = 0; i < 4; ++i) {
    const int row = bx * 64 + r + i * 16;
    float4 v = *(const float4*)&w[row * 1024 + by * 64 + c4 * 4];
    t[r + i * 16][c4 * 4 + 0] = v.x;
    t[r + i * 16][c4 * 4 + 1] = v.y;
    t[r + i * 16][c4 * 4 + 2] = v.z;
    t[r + i * 16][c4 * 4 + 3] = v.w;
  }
  __syncthreads();
  const int l = threadIdx.x & 63, og = threadIdx.x >> 6;
#pragma unroll
  for (int j = 0; j < 16; ++j) {
    const int o_local = og + j * 4;
    t16[(by * 64 + o_local) * 1024 + bx * 64 + l] = f2h(t[l][o_local]);
  }
}

// merged memory-slot fills + mask tail words.
__global__ void fill_all_kernel(const float* __restrict__ m_k,
                                const float* __restrict__ m_v,
                                u16* __restrict__ kh, u16* __restrict__ vt,
                                u32* __restrict__ mbits) {
  const int bi = blockIdx.x;
  if (bi < 2048) {
    int idx = bi * 256 + threadIdx.x;           // 64*64*128 = 524288
    int bh = idx >> 13, ko = (idx >> 7) & 63, dk = idx & 127;
    int h = bh & 7;
    float v = 0.f;
    if (ko < 16) v = 11.313708498984760f * m_k[ko * 1024 + h * 128 + dk];
    kh[((size_t)bh * KSP + 1024 + ko) * 128 + dk] = f2h(v);
  } else if (bi < 4096) {
    int idx = (bi - 2048) * 256 + threadIdx.x;  // 64*128*64 = 524288
    int bh = idx >> 13, dv = (idx >> 6) & 127, ko = idx & 63;
    int h = bh & 7;
    float v = (ko < 16) ? 4.0f * m_v[ko * 1024 + h * 128 + dv] : 0.f;
    vt[((size_t)bh * 128 + dv) * KSP + 1024 + ko] = f2h(v);
  } else {
    int idx = (bi - 4096) * 256 + threadIdx.x;  // 65536
    mbits[idx * MW + 32] = 0xFFFF0000u;
    mbits[idx * MW + 33] = 0xFFFFFFFFu;
  }
}

// mask (int32, !=0 dead) -> bit words. mbits[(bh*1024+q)*34 + w].
__global__ void maskbits_kernel(const int* __restrict__ mask, u32* __restrict__ mbits) {
  const int lane = threadIdx.x & 63;
  const int nwave = (gridDim.x * blockDim.x) >> 6;
  int wid = (blockIdx.x * blockDim.x + threadIdx.x) >> 6;
  for (int g = wid; g < 262144; g += nwave) {       // 256-key groups
    const int4 m = *(const int4*)&mask[(size_t)g * 256 + lane * 4];
    u32 nib = (m.x ? 1u : 0u) | (m.y ? 2u : 0u) | (m.z ? 4u : 0u) | (m.w ? 8u : 0u);
    u32 v = nib << ((lane & 7) * 4);
    v |= __shfl_xor(v, 1);
    v |= __shfl_xor(v, 2);
    v |= __shfl_xor(v, 4);
    if ((lane & 7) == 0) {
      const int row = g >> 2;                        // (bh*1024+q)
      const int word = ((g & 3) << 3) + (lane >> 3); // 0..31
      mbits[row * MW + word] = v;
    }
  }
}

// ---------------------------------------------------------------------- GEMM
// C(8192x1024) = A(8192x1024) @ B^T, B given as (1024 n-rows x 1024 k) rm.
// 128x128 tile, BK=64, 4 waves (2x2), 4x4 16x16x32 fp16 fragments per wave.
// R7 mapping: bm = blockIdx & 63 (inner), bn = blockIdx >> 6.
__device__ __forceinline__ void stage_tile(const u16* __restrict__ gbase,
                                           u16* sbase, int w, int lane) {
#pragma unroll
  for (int i = 0; i < 4; ++i) {
    const u16* src = gbase + (w * 32 + i * 8 + (lane >> 3)) * 1024 + (lane & 7) * 8;
    u16* dst = sbase + (w * 32 + i * 8) * 64;
    __builtin_amdgcn_global_load_lds(
        (const __attribute__((address_space(1))) void*)src,
        (__attribute__((address_space(3))) void*)dst, 16, 0, 0);
  }
}

enum { EPI_Q16 = 0, EPI_K16 = 1, EPI_VT = 2, EPI_OUT = 3 };

template <int EPI>
__global__ __launch_bounds__(256)
void gemm_kernel(const u16* __restrict__ A, const u16* __restrict__ B,
                 const float* __restrict__ bias,
                 u16* __restrict__ oH, float* __restrict__ oF) {
  __shared__ u16 sA[128 * 64];
  __shared__ u16 sB[128 * 64];
  const int lane = threadIdx.x & 63, w = threadIdx.x >> 6;
  const int bm = blockIdx.x & 63, bn = blockIdx.x >> 6;
  const int wr = w >> 1, wc = w & 1;

  f32x4 acc[4][4];
  const f32x4 fz = {0.f, 0.f, 0.f, 0.f};
#pragma unroll
  for (int m = 0; m < 4; ++m)
#pragma unroll
    for (int n = 0; n < 4; ++n) acc[m][n] = fz;

  for (int kt = 0; kt < 16; ++kt) {
    const int kb = kt * 64;
    stage_tile(A + bm * 128 * 1024 + kb, sA, w, lane);
    stage_tile(B + bn * 128 * 1024 + kb, sB, w, lane);
    __syncthreads();
    const int ro = lane & 15;
#pragma unroll
    for (int kk = 0; kk < 2; ++kk) {
      const int co = kk * 32 + (lane >> 4) * 8;
      f16x8 a[4], b[4];
#pragma unroll
      for (int m = 0; m < 4; ++m) a[m] = ld_h8(&sA[(wr * 64 + m * 16 + ro) * 64 + co]);
#pragma unroll
      for (int n = 0; n < 4; ++n) b[n] = ld_h8(&sB[(wc * 64 + n * 16 + ro) * 64 + co]);
#pragma unroll
      for (int m = 0; m < 4; ++m)
#pragma unroll
        for (int n = 0; n < 4; ++n)
          acc[m][n] = MFMA_F16(a[m], b[n], acc[m][n]);
    }
    __syncthreads();
  }

  // epilogue
#pragma unroll
  for (int m = 0; m < 4; ++m)
#pragma unroll
    for (int n = 0; n < 4; ++n) {
      const int row0 = bm * 128 + wr * 64 + m * 16 + ((lane >> 4) << 2);
      const int col = bn * 128 + wc * 64 + n * 16 + (lane & 15);
      const float bv_ = bias[col];
#pragma unroll
      for (int r = 0; r < 4; ++r) {
        const float y = acc[m][n][r] + bv_;
        const int row = row0 + r;
        if constexpr (EPI == EPI_Q16) {
          oH[row * 1024 + col] = f2h(y * SCALE_QK);   // scale folded into Q
        } else if constexpr (EPI == EPI_K16) {
          const int b = row >> 10, key = row & 1023;
          oH[((size_t)(b * 8 + (col >> 7)) * KSP + key) * 128 + (col & 127)] = f2h(y);
        } else if constexpr (EPI == EPI_VT) {
          const int b = row >> 10, key = row & 1023;
          oH[((size_t)(b * 8 + (col >> 7)) * 128 + (col & 127)) * KSP + key] = f2h(y);
        } else {
          oF[row * 1024 + col] = y;
        }
      }
    }
}

// ----------------------------------------------------------------- attention
// R7-verified structure. 4 waves/block, 16 q-rows/wave, 1024 blocks (64 bh x
// 16 qblk, bh-per-XCD). Phase 1: 17 x 64-key chunks, QK^T+exp -> lsum only.
// Shuffle-reduce -> inv[4] in regs. Phase 2: 17 x 64-key chunks, QK^T
// recomputed (K L2-hot), e*inv -> normalized att + PV. T14 reg-staging,
// XOR-swizzled K LDS. O written via LDS re-tile (coalesced 16B stores).
__global__ __launch_bounds__(256, 3)
void attn_kernel(const u16* __restrict__ qh, const u16* __restrict__ kh,
                 const u16* __restrict__ vt, const u32* __restrict__ mbits,
                 float* __restrict__ att, u16* __restrict__ obuf) {
  __shared__ __align__(16) u16 sK[64 * 128];        // 16 KB
  __shared__ __align__(16) u16 sV[128 * 72];        // 18 KB (144B rows)
  __shared__ __align__(16) float sAtt[4][16][36];   // 9 KB
  const int tid = threadIdx.x;
  const int lane = tid & 63, w = tid >> 6;

  // XCD swizzle: XCD x owns bh in [x*8, x*8+8), 16 qblks each.
  const int d = blockIdx.x;                  // 1024 blocks
  const int j = d >> 3;
  const int bh = (d & 7) * 8 + (j >> 4);
  const int qblk = j & 15;
  const int h = bh & 7;
  const int b = bh >> 3;
  const int qrow0 = qblk * 64 + w * 16;       // within NQ
  const int grow0 = b * NQS + qrow0;          // row in (8192 x 1024) Q/O buffers
  const int ro = lane & 15, go = lane >> 4;

  // Q fragments (held for whole kernel)
  f16x8 qf[4];
#pragma unroll
  for (int kk = 0; kk < 4; ++kk)
    qf[kk] = ld_h8(&qh[(grow0 + ro) * 1024 + h * 128 + kk * 32 + go * 8]);

  const u16* khb = kh + (size_t)bh * KSP * 128;
  const u16* vtb = vt + (size_t)bh * 128 * KSP;
  const u32* mbb = mbits + (size_t)bh * NQS * MW;
  float* attb = att + (size_t)(bh * NQS + qrow0) * NKM;

  // K staging geometry: 4 x 16B per thread (rows r_k, +16, +32, +48)
  const int r_k  = tid >> 4;               // 0..15
  const int cb_k = (tid & 15) * 16;        // byte col in 256B row
  const u16* kp0 = khb + r_k * 128 + (cb_k >> 1);
  const int dk0 = r_k * 256 + (cb_k ^ ((r_k & 7) << 4));   // xor invariant to +16 rows
  // V staging geometry: 4 x 16B per thread; t = p*256+tid: row t>>3, chunk t&7
  const int vrow[4] = {(0 * 256 + tid) >> 3, (1 * 256 + tid) >> 3,
                       (2 * 256 + tid) >> 3, (3 * 256 + tid) >> 3};
  const int vc8[4]  = {(0 * 256 + tid) & 7, (1 * 256 + tid) & 7,
                       (2 * 256 + tid) & 7, (3 * 256 + tid) & 7};

  const f32x4 fz = {0.f, 0.f, 0.f, 0.f};
  float lsum[4] = {0.f, 0.f, 0.f, 0.f};

  // ================= phase 1: row sums (17 x 64-key chunks) ===============
  {
    s16x8 rk0 = *(const s16x8*)(kp0);
    s16x8 rk1 = *(const s16x8*)(kp0 + 16 * 128);
    s16x8 rk2 = *(const s16x8*)(kp0 + 32 * 128);
    s16x8 rk3 = *(const s16x8*)(kp0 + 48 * 128);
    for (int c = 0; c < 17; ++c) {
      __syncthreads();
      *(s16x8*)((char*)sK + dk0)         = rk0;
      *(s16x8*)((char*)sK + dk0 + 4096)  = rk1;
      *(s16x8*)((char*)sK + dk0 + 8192)  = rk2;
      *(s16x8*)((char*)sK + dk0 + 12288) = rk3;
      if (c < 16) {
        const u16* p = kp0 + (c + 1) * 64 * 128;
        rk0 = *(const s16x8*)(p);
        rk1 = *(const s16x8*)(p + 16 * 128);
        rk2 = *(const s16x8*)(p + 32 * 128);
        rk3 = *(const s16x8*)(p + 48 * 128);
      }
      __syncthreads();
      u32 mw0[4], mw1[4];
#pragma unroll
      for (int r = 0; r < 4; ++r) {
        const int row = qrow0 + (go << 2) + r;
        uint2 mm = *(const uint2*)&mbb[row * MW + 2 * c];
        mw0[r] = mm.x;
        mw1[r] = mm.y;
      }
#pragma unroll
      for (int t = 0; t < 4; ++t) {
        f32x4 s = fz;
        const int rr = t * 16 + ro;
        const int sw = (rr & 7) << 4;
        __builtin_amdgcn_s_setprio(1);
#pragma unroll
        for (int kk = 0; kk < 4; ++kk) {
          const int off = rr * 256 + ((kk * 64 + go * 16) ^ sw);
          s = MFMA_F16(qf[kk], ld_h8((const u16*)((const char*)sK + off)), s);
        }
        __builtin_amdgcn_s_setprio(0);
        const int bit = (t & 1) * 16 + ro;
#pragma unroll
        for (int r = 0; r < 4; ++r) {
          const u32 mw = (t < 2) ? mw0[r] : mw1[r];
          const bool dead = (mw >> bit) & 1;
          lsum[r] += dead ? 0.f : __expf(s[r]);
        }
      }
    }
  }

  // reduce across the 16 ro-lanes of each go-group -> every lane holds inv[]
  float inv[4];
#pragma unroll
  for (int r = 0; r < 4; ++r) {
    lsum[r] += __shfl_xor(lsum[r], 1);
    lsum[r] += __shfl_xor(lsum[r], 2);
    lsum[r] += __shfl_xor(lsum[r], 4);
    lsum[r] += __shfl_xor(lsum[r], 8);
    inv[r] = 1.0f / lsum[r];
  }

  // ================= phase 2: normalized att + PV =========================
  f32x4 oacc[8];
#pragma unroll
  for (int n = 0; n < 8; ++n) oacc[n] = fz;

  s16x8 rk0 = *(const s16x8*)(kp0);
  s16x8 rk1 = *(const s16x8*)(kp0 + 16 * 128);
  s16x8 rk2 = *(const s16x8*)(kp0 + 32 * 128);
  s16x8 rk3 = *(const s16x8*)(kp0 + 48 * 128);
  s16x8 rv0 = *(const s16x8*)(vtb + (size_t)vrow[0] * KSP + vc8[0] * 8);
  s16x8 rv1 = *(const s16x8*)(vtb + (size_t)vrow[1] * KSP + vc8[1] * 8);
  s16x8 rv2 = *(const s16x8*)(vtb + (size_t)vrow[2] * KSP + vc8[2] * 8);
  s16x8 rv3 = *(const s16x8*)(vtb + (size_t)vrow[3] * KSP + vc8[3] * 8);

  for (int c = 0; c < 17; ++c) {
    __syncthreads();                       // previous chunk fully consumed
    *(s16x8*)((char*)sK + dk0)         = rk0;
    *(s16x8*)((char*)sK + dk0 + 4096)  = rk1;
    *(s16x8*)((char*)sK + dk0 + 8192)  = rk2;
    *(s16x8*)((char*)sK + dk0 + 12288) = rk3;
    *(s16x8*)((char*)sV + vrow[0] * 144 + vc8[0] * 16) = rv0;
    *(s16x8*)((char*)sV + vrow[1] * 144 + vc8[1] * 16) = rv1;
    *(s16x8*)((char*)sV + vrow[2] * 144 + vc8[2] * 16) = rv2;
    *(s16x8*)((char*)sV + vrow[3] * 144 + vc8[3] * 16) = rv3;
    if (c < 16) {                          // issue next chunk's loads
      const int nkb = (c + 1) * 64;
      const u16* p = kp0 + nkb * 128;
      rk0 = *(const s16x8*)(p);
      rk1 = *(const s16x8*)(p + 16 * 128);
      rk2 = *(const s16x8*)(p + 32 * 128);
      rk3 = *(const s16x8*)(p + 48 * 128);
      rv0 = *(const s16x8*)(vtb + (size_t)vrow[0] * KSP + nkb + vc8[0] * 8);
      rv1 = *(const s16x8*)(vtb + (size_t)vrow[1] * KSP + nkb + vc8[1] * 8);
      rv2 = *(const s16x8*)(vtb + (size_t)vrow[2] * KSP + nkb + vc8[2] * 8);
      rv3 = *(const s16x8*)(vtb + (size_t)vrow[3] * KSP + nkb + vc8[3] * 8);
    }
    __syncthreads();                       // chunk c ready

    u32 mwc[2][4];
#pragma unroll
    for (int r = 0; r < 4; ++r) {
      const int row = qrow0 + (go << 2) + r;
      uint2 mm = *(const uint2*)&mbb[row * MW + 2 * c];
      mwc[0][r] = mm.x;
      mwc[1][r] = mm.y;
    }

#pragma unroll
    for (int t2 = 0; t2 < 2; ++t2) {
#pragma unroll
      for (int t = 0; t < 2; ++t) {
        f32x4 s = fz;
        const int rr = t2 * 32 + t * 16 + ro;        // key row in 64-chunk
        const int sw = (rr & 7) << 4;
        __builtin_amdgcn_s_setprio(1);
#pragma unroll
        for (int kk = 0; kk < 4; ++kk) {
          const int off = rr * 256 + ((kk * 64 + go * 16) ^ sw);
          s = MFMA_F16(qf[kk], ld_h8((const u16*)((const char*)sK + off)), s);
        }
        __builtin_amdgcn_s_setprio(0);
        const int bit = t * 16 + ro;
#pragma unroll
        for (int r = 0; r < 4; ++r) {
          const int lrow = (go << 2) + r;
          const bool dead = (mwc[t2][r] >> bit) & 1;
          const float e = dead ? 0.f : __expf(s[r]);
          sAtt[w][lrow][t * 16 + ro] = e * inv[r];   // normalized
        }
      }

      // att writeout (normalized): 4 lanes cover one row's 32 f32 (128B)
      {
        const int kbh = c * 64 + t2 * 32;
        const int arow = lane >> 2, cg = lane & 3;
        if (kbh + cg * 8 < NKM) {
          f32x4 v0 = *(const f32x4*)&sAtt[w][arow][cg * 8];
          f32x4 v1 = *(const f32x4*)&sAtt[w][arow][cg * 8 + 4];
          float* dst = attb + (size_t)arow * NKM + kbh + cg * 8;
          *(f32x4*)dst = v0;
          *(f32x4*)(dst + 4) = v1;
        }
      }

      // PV with normalized p (A rows=q, cols=key), B rows=dv from sV
      {
        f32x4 p0 = *(const f32x4*)&sAtt[w][ro][go * 8];
        f32x4 p1 = *(const f32x4*)&sAtt[w][ro][go * 8 + 4];
        f16x8 pa;
        pa[0] = (_Float16)p0[0]; pa[1] = (_Float16)p0[1];
        pa[2] = (_Float16)p0[2]; pa[3] = (_Float16)p0[3];
        pa[4] = (_Float16)p1[0]; pa[5] = (_Float16)p1[1];
        pa[6] = (_Float16)p1[2]; pa[7] = (_Float16)p1[3];
        __builtin_amdgcn_s_setprio(1);
#pragma unroll
        for (int n = 0; n < 8; ++n) {
          f16x8 vb = ld_h8((const u16*)((const char*)sV + (n * 16 + ro) * 144 + t2 * 64 + go * 16));
          oacc[n] = MFMA_F16(pa, vb, oacc[n]);
        }
        __builtin_amdgcn_s_setprio(0);
      }
    }
  }

  // O writeout via LDS re-tile: wave w stages 16 rows x 128 cols fp16 at
  // sK + w*4096, then 16B coalesced stores (16 lanes cover one 256B row).
  __syncthreads();
  {
    u16* os = (u16*)((char*)sK + w * 4096);
#pragma unroll
    for (int n = 0; n < 8; ++n)
#pragma unroll
      for (int r = 0; r < 4; ++r)
        os[((go << 2) + r) * 128 + n * 16 + ro] = f2h(oacc[n][r]);
#pragma unroll
    for (int i = 0; i < 4; ++i) {
      const int idx = i * 64 + lane;            // 0..255
      const int row = idx >> 4, c16 = idx & 15; // 16 rows x 16 chunks
      s16x8 v = *(const s16x8*)(os + row * 128 + c16 * 8);
      *(s16x8*)&obuf[(size_t)(grow0 + row) * 1024 + h * 128 + c16 * 8] = v;
    }
  }
}

// --------------------------------------------------------------------- launch
extern "C" void kernel_launch(void* const* d_in, const int* in_sizes, int n_in,
                              void* d_out, int out_size, void* d_ws, size_t ws_size,
                              hipStream_t stream) {
  const float* queries = (const float*)d_in[0];
  const float* keys    = (const float*)d_in[1];
  const float* values  = (const float*)d_in[2];
  const int*   mask    = (const int*)d_in[3];
  const float* Wq = (const float*)d_in[4];
  const float* bq = (const float*)d_in[5];
  const float* Wk = (const float*)d_in[6];
  const float* bk = (const float*)d_in[7];
  const float* Wv = (const float*)d_in[8];
  const float* bv = (const float*)d_in[9];
  const float* Wo = (const float*)d_in[10];
  const float* bo = (const float*)d_in[11];
  const float* m_k = (const float*)d_in[12];
  const float* m_v = (const float*)d_in[13];

  if (ws_size < 136839168) return;   // layout below needs ~130.5 MiB

  char* ws = (char*)d_ws;
  u16* xq  = (u16*)(ws + 0);           // 16 MiB (xq/xk/xv contiguous)
  u16* xk  = (u16*)(ws + 16777216);    // 16 MiB
  u16* xv  = (u16*)(ws + 33554432);    // 16 MiB
  u16* wq  = (u16*)(ws + 50331648);    // 2 MiB
  u16* wk  = (u16*)(ws + 52428800);
  u16* wv  = (u16*)(ws + 54525952);
  u16* wo  = (u16*)(ws + 56623104);
  u16* q16 = (u16*)(ws + 58720256);    // 16 MiB
  u16* k16 = (u16*)(ws + 75497472);    // 64*1088*128*2 = 17 MiB
  u16* vt  = (u16*)(ws + 93323264);    // 17 MiB
  u16* obuf= (u16*)(ws + 111149056);   // 16 MiB
  u32* mbits=(u32*)(ws + 127926272);   // 8.9 MiB

  float* out = (float*)d_out;
  float* att = out + 8388608;

  // 1. input converts (f32 -> fp16), one dispatch
  cvt16_all_kernel<<<6144, 256, 0, stream>>>(queries, keys, values, xq);
  // 2. weight transposes (LDS-tiled, fp16), one dispatch
  wtrans16_all_kernel<<<1024, 256, 0, stream>>>(Wq, Wk, Wv, Wo, wq, wk, wv, wo);
  // 3. projections (128x128-tile fp16 GEMMs, R7 mapping; Q folds SCALE_QK)
  gemm_kernel<EPI_Q16><<<512, 256, 0, stream>>>(xq, wq, bq, q16, nullptr);
  gemm_kernel<EPI_K16><<<512, 256, 0, stream>>>(xk, wk, bk, k16, nullptr);
  gemm_kernel<EPI_VT> <<<512, 256, 0, stream>>>(xv, wv, bv, vt,  nullptr);
  // 4. mask bit-pack
  maskbits_kernel<<<2048, 256, 0, stream>>>(mask, mbits);
  // 5. memory-slot fills + mask tail words, one dispatch
  fill_all_kernel<<<4352, 256, 0, stream>>>(m_k, m_v, k16, vt, mbits);
  // 6. attention (normalized att + O in one kernel, two-pass over K)
  attn_kernel<<<1024, 256, 0, stream>>>(q16, k16, vt, mbits, att, obuf);
  // 7. output projection
  gemm_kernel<EPI_OUT><<<512, 256, 0, stream>>>(obuf, wo, bo, nullptr, out);
}